// Round 3
// baseline (127.033 us; speedup 1.0000x reference)
//
#include <hip/hip_runtime.h>
#include <math.h>

#define BLOCK 256
#define NN 100
#define GB 10           // boxes per pass-B block
#define NGRP (NN / GB)  // 10 box-groups per image
#define SPLIT 16        // anchor-dimension splits for pass B
#define NBINS 4096      // 64 x-cells * 64 y-cells (16px each)

__device__ __forceinline__ float fast_rcp(float x) { return __builtin_amdgcn_rcpf(x); }

__device__ __forceinline__ int cell_key(float cx, float cy) {
    int kx = (int)(cx * (64.0f / 1024.0f));
    int ky = (int)(cy * (64.0f / 1024.0f));
    kx = kx < 0 ? 0 : (kx > 63 ? 63 : kx);
    ky = ky < 0 ? 0 : (ky > 63 ? 63 : ky);
    return (kx << 6) | ky;
}

// ---------------------------------------------------------------------------
// Spatial counting sort of anchors (data-dependent, redone every call).
// Sorted order gives each wave a ~16x64px region -> per-(wave,box) ballot
// skip. All downstream argmax keys use ORIGINAL indices.
// ---------------------------------------------------------------------------
__global__ void __launch_bounds__(BLOCK) bbp_hist(
    const float* __restrict__ anchors, int* __restrict__ hist, int A) {
    int i = blockIdx.x * BLOCK + threadIdx.x;
    if (i >= A) return;
    float4 ac = *(const float4*)(anchors + (size_t)i * 4);
    atomicAdd(&hist[cell_key(ac.x, ac.y)], 1);
}

// single wave: in-place exclusive scan of 4096 bins
__global__ void __launch_bounds__(64) bbp_scan(int* __restrict__ hist) {
    const int lane = threadIdx.x;              // 0..63
    const int base = lane * (NBINS / 64);      // 64 bins per lane
    int vals[NBINS / 64];
    int sum = 0;
    #pragma unroll
    for (int k = 0; k < NBINS / 64; ++k) { vals[k] = hist[base + k]; sum += vals[k]; }
    int incl = sum;
    #pragma unroll
    for (int off = 1; off < 64; off <<= 1) {
        int o = __shfl_up(incl, off, 64);
        if (lane >= off) incl += o;
    }
    int run = incl - sum;                      // exclusive prefix of this chunk
    #pragma unroll
    for (int k = 0; k < NBINS / 64; ++k) { hist[base + k] = run; run += vals[k]; }
}

__global__ void __launch_bounds__(BLOCK) bbp_scatter(
    const float* __restrict__ anchors, int* __restrict__ off,
    float4* __restrict__ scor, float2* __restrict__ smeta, int A) {
    int i = blockIdx.x * BLOCK + threadIdx.x;
    if (i >= A) return;
    float4 ac = *(const float4*)(anchors + (size_t)i * 4);
    int pos = atomicAdd(&off[cell_key(ac.x, ac.y)], 1);
    float4 c;
    c.x = fmaf(ac.z, -0.5f, ac.x);
    c.y = fmaf(ac.w, -0.5f, ac.y);
    c.z = fmaf(ac.z, 0.5f, ac.x);
    c.w = fmaf(ac.w, 0.5f, ac.y);
    scor[pos] = c;                             // pre-decoded corners
    smeta[pos] = make_float2(ac.z * ac.w, __int_as_float(i));  // area, orig idx
}

// ---------------------------------------------------------------------------
// Fused match kernel on SORTED anchors with nested ballot skip.
// CORRECTNESS KEY (R2 bug fix): init state is (inter=0, s=1, idx=0), so the
// update test  fmaf(inter, s_best, -(in_best*s)) > 0  degenerates to
// inter > 0 while in_best == 0 -- only GENUINE overlaps ever update.
// All-skip rows/columns therefore keep idx=0, exactly matching the
// reference argmax-of-zero-row/column (= index 0) semantics, even though
// the ballot skips arbitrary subsets of zero-IoU pairs. (The old (-1,1)
// init let balloted-in inter==0 pairs capture the argmax -> wrong deltas.)
// ---------------------------------------------------------------------------
__global__ void __launch_bounds__(BLOCK, 4) bbp_fused(
    const float4* __restrict__ scor, const float2* __restrict__ smeta,
    const float* __restrict__ bboxes,
    float2* __restrict__ pa,                      // [B*A] (row max iou, idx)
    unsigned long long* __restrict__ packed_part, // [B,N,SPLIT]
    int A, int NA, int NBB) {
    const int bid = blockIdx.x;
    const int tid = threadIdx.x;

    if (bid < NBB) {
        // ========== pass B: per-box partial max over one sorted slab ========
        const int b   = bid / (NGRP * SPLIT);
        const int rem = bid - b * (NGRP * SPLIT);
        const int ng  = rem / SPLIT;
        const int sp  = rem - ng * SPLIT;
        const int n0  = ng * GB;
        const int SA  = A / SPLIT;                // 4096 anchors per slab
        const int abase = sp * SA;
        const float* bb = bboxes + ((size_t)b * NN + n0) * 4;

        float bx1[GB], by1[GB], bx2[GB], by2[GB], sa[GB];
        #pragma unroll
        for (int g = 0; g < GB; ++g) {
            float4 v = *(const float4*)(bb + 4 * g);     // uniform -> s_load
            bx1[g] = v.x; by1[g] = v.y; bx2[g] = v.z; by2[g] = v.w;
            sa[g] = (v.z - v.x) * (v.w - v.y);
        }
        float cin[GB], cs[GB];
        int cai[GB];
        #pragma unroll
        for (int g = 0; g < GB; ++g) { cin[g] = 0.0f; cs[g] = 1.0f; cai[g] = 0; }

        const int iters = SA >> 8;                       // 16
        #pragma unroll 2
        for (int j = 0; j < iters; ++j) {
            const int t = abase + j * BLOCK + tid;
            const float4 c = scor[t];                    // coalesced
            const float2 m = smeta[t];
            const float area_a = m.x;
            const int orig = __float_as_int(m.y);
            #pragma unroll
            for (int g = 0; g < GB; ++g) {
                float w0 = fminf(c.z, bx2[g]) - fmaxf(c.x, bx1[g]);
                if (__any(w0 > 0.0f)) {                  // wave-uniform x skip
                    float h0 = fminf(c.w, by2[g]) - fmaxf(c.y, by1[g]);
                    if (__any(h0 > 0.0f)) {              // wave-uniform y skip
                        float inter = fmaxf(w0, 0.0f) * fmaxf(h0, 0.0f);
                        float s = area_a + sa[g];
                        if (fmaf(inter, cs[g], -(cin[g] * s)) > 0.0f) {
                            cin[g] = inter; cs[g] = s; cai[g] = orig;
                        }
                    }
                }
            }
        }

        // once-per-block combine: shfl-u64 wave reduce -> LDS -> plain store
        __shared__ unsigned long long sred[GB][BLOCK / 64];
        #pragma unroll
        for (int g = 0; g < GB; ++g) {
            float iou = fmaxf(cin[g] * fast_rcp(cs[g] - cin[g]), 0.0f);
            unsigned long long pk =
                ((unsigned long long)__float_as_uint(iou) << 32)
                | (unsigned long long)(0xFFFFFFFFu - (unsigned)cai[g]);
            #pragma unroll
            for (int off = 32; off > 0; off >>= 1) {
                unsigned long long o = __shfl_down(pk, off, 64);
                if (o > pk) pk = o;
            }
            if ((tid & 63) == 0) sred[g][tid >> 6] = pk;
        }
        __syncthreads();
        if (tid < GB) {
            unsigned long long mx = sred[tid][0];
            #pragma unroll
            for (int j = 1; j < BLOCK / 64; ++j) {
                unsigned long long o = sred[tid][j];
                if (o > mx) mx = o;
            }
            packed_part[((size_t)b * NN + n0 + tid) * SPLIT + sp] = mx;
        }
    } else {
        // ========== pass A: per-anchor row max over boxes ===================
        const int abid = bid - NBB;
        const int b = abid / NA;
        const int t = (abid - b * NA) * BLOCK + tid;     // sorted position

        __shared__ float sbarea[NN];
        if (tid < NN) {
            float4 v = *(const float4*)(bboxes + ((size_t)b * NN + tid) * 4);
            sbarea[tid] = (v.z - v.x) * (v.w - v.y);
        }
        __syncthreads();

        const float4 c = scor[t];
        const float2 mt = smeta[t];
        const float area_a = mt.x;
        const int orig = __float_as_int(mt.y);
        const float* bbase = bboxes + (size_t)b * NN * 4;   // wave-uniform

        float in0 = 0.0f, s0 = 1.0f;   // see CORRECTNESS KEY above
        int i0 = 0;
        #pragma unroll 4
        for (int n = 0; n < NN; ++n) {
            const float4 v = *(const float4*)(bbase + 4 * n);  // s_load
            float w0 = fminf(c.z, v.z) - fmaxf(c.x, v.x);
            if (__any(w0 > 0.0f)) {
                float h0 = fminf(c.w, v.w) - fmaxf(c.y, v.y);
                if (__any(h0 > 0.0f)) {
                    float inter = fmaxf(w0, 0.0f) * fmaxf(h0, 0.0f);
                    float s = area_a + sbarea[n];
                    if (fmaf(inter, s0, -(in0 * s)) > 0.0f) {
                        in0 = inter; s0 = s; i0 = n;
                    }
                }
            }
        }
        const size_t idx = (size_t)b * A + orig;
        float2 r;
        r.x = in0 * fast_rcp(s0 - in0);   // zero row -> 0 * rcp(1) = 0
        r.y = __int_as_float(i0);
        pa[idx] = r;                                     // scattered 8B, L2
    }
}

// ---------------------------------------------------------------------------
// Finalize: reduce SPLIT partials per box in LDS, override scatter via LDS
// atomicMax, score + one-hot conf + delta encoding. (Unchanged.)
// ---------------------------------------------------------------------------
__global__ void __launch_bounds__(BLOCK) bbp_finalize(
    const float* __restrict__ anchors, const float* __restrict__ bboxes,
    const int* __restrict__ labels, const float* __restrict__ mean4,
    const float* __restrict__ std4, const float* __restrict__ thr_p,
    const float2* __restrict__ pa,
    const unsigned long long* __restrict__ packed_part,
    float* __restrict__ out_conf, float* __restrict__ out_deltas,
    int A, int C) {
    const int b = blockIdx.y;
    const int tid = threadIdx.x;

    __shared__ float smax[NN];    // max_iou_of_bbox
    __shared__ float4 sbox[NN];   // gt boxes
    __shared__ int slab[NN];      // labels
    __shared__ int sovr[BLOCK];   // override winner per local anchor (-1 none)
    sovr[tid] = -1;
    __syncthreads();
    if (tid < NN) {
        const ulonglong2* pp =
            (const ulonglong2*)(packed_part + ((size_t)b * NN + tid) * SPLIT);
        unsigned long long m = 0;
        #pragma unroll
        for (int j = 0; j < SPLIT / 2; ++j) {
            ulonglong2 v = pp[j];
            if (v.x > m) m = v.x;
            if (v.y > m) m = v.y;
        }
        smax[tid] = __uint_as_float((unsigned)(m >> 32));
        unsigned an = 0xFFFFFFFFu - (unsigned)(m & 0xFFFFFFFFull);
        // segment_max over target ids: larger n wins -> atomicMax
        if ((an >> 8) == (unsigned)blockIdx.x)
            atomicMax(&sovr[an & (BLOCK - 1)], tid);
        slab[tid] = labels[(size_t)b * NN + tid];
        sbox[tid] = *(const float4*)(bboxes + ((size_t)b * NN + tid) * 4);
    }
    __syncthreads();

    const int a = blockIdx.x * BLOCK + tid;
    const size_t idx = (size_t)b * A + a;
    const float thr = thr_p[0];

    float2 pav = pa[idx];
    int ov = sovr[tid];
    bool valid = ov >= 0;
    int bi = valid ? ov : __float_as_int(pav.y);
    float mb = smax[bi];                      // max_iou_of_bbox[bi]
    float miou = valid ? mb : pav.x;
    float denom = fmaxf(mb, thr);
    if (miou < 0.5f * thr) miou = 0.0f;
    float score = miou * fast_rcp(denom);
    int lab = slab[bi];
    if (lab <= 0) { score = 0.0f; lab = 0; }

    for (int c = 0; c < C; ++c)
        out_conf[idx * (size_t)C + c] = (lab == c + 1) ? score : 0.0f;

    float4 bv = sbox[bi];
    float4 av = *(const float4*)(anchors + (size_t)a * 4);
    float cx = (bv.x + bv.z) * 0.5f;
    float cy = (bv.y + bv.w) * 0.5f;
    float bw = bv.z - bv.x;
    float bh = bv.w - bv.y;
    const float rz = fast_rcp(av.z), rw = fast_rcp(av.w);
    float4 d;
    d.x = ((cx - av.x) * rz - mean4[0]) * fast_rcp(std4[0]);
    d.y = ((cy - av.y) * rw - mean4[1]) * fast_rcp(std4[1]);
    d.z = (__logf(bw * rz) - mean4[2]) * fast_rcp(std4[2]);
    d.w = (__logf(bh * rw) - mean4[3]) * fast_rcp(std4[3]);
    *(float4*)(out_deltas + idx * 4) = d;
}

// ---------------------------------------------------------------------------
extern "C" void kernel_launch(void* const* d_in, const int* in_sizes, int n_in,
                              void* d_out, int out_size, void* d_ws, size_t ws_size,
                              hipStream_t stream) {
    const float* anchors = (const float*)d_in[0];
    const int* labels = (const int*)d_in[1];
    const float* bboxes = (const float*)d_in[2];
    const float* mean4 = (const float*)d_in[3];
    const float* std4 = (const float*)d_in[4];
    const float* thr_p = (const float*)d_in[5];

    const int A = in_sizes[0] / 4;        // 65536
    const int BN = in_sizes[1];           // 800
    const int B = BN / NN;                // 8
    const int C = out_size / (B * A) - 4; // 1
    const int NA = A / BLOCK;             // 256 pass-A block-groups per image
    const int NAB = B * NA;               // 2048 pass-A blocks
    const int NBB = B * NGRP * SPLIT;     // 1280 pass-B blocks

    char* ws = (char*)d_ws;
    size_t off = 0;
    int* hist = (int*)ws;                                         // [4096]
    off += ((size_t)NBINS * sizeof(int) + 255) & ~(size_t)255;
    float4* scor = (float4*)(ws + off);                           // [A]
    off += ((size_t)A * sizeof(float4) + 255) & ~(size_t)255;
    float2* smeta = (float2*)(ws + off);                          // [A]
    off += ((size_t)A * sizeof(float2) + 255) & ~(size_t)255;
    unsigned long long* packed_part = (unsigned long long*)(ws + off); // [B*N*SPLIT]
    off += ((size_t)B * NN * SPLIT * sizeof(unsigned long long) + 255) & ~(size_t)255;
    float2* pa = (float2*)(ws + off);                             // [B*A]

    float* out_conf = (float*)d_out;
    float* out_deltas = out_conf + (size_t)B * A * C;

    hipMemsetAsync(hist, 0, NBINS * sizeof(int), stream);
    bbp_hist<<<dim3(A / BLOCK), dim3(BLOCK), 0, stream>>>(anchors, hist, A);
    bbp_scan<<<dim3(1), dim3(64), 0, stream>>>(hist);
    bbp_scatter<<<dim3(A / BLOCK), dim3(BLOCK), 0, stream>>>(anchors, hist, scor, smeta, A);

    bbp_fused<<<dim3(NBB + NAB), dim3(BLOCK), 0, stream>>>(
        scor, smeta, bboxes, pa, packed_part, A, NA, NBB);

    bbp_finalize<<<dim3(A / BLOCK, B), dim3(BLOCK), 0, stream>>>(
        anchors, bboxes, labels, mean4, std4, thr_p, pa, packed_part,
        out_conf, out_deltas, A, C);
}